// Round 5
// baseline (358.669 us; speedup 1.0000x reference)
//
#include <hip/hip_runtime.h>
#include <hip/hip_bf16.h>
#include <math.h>

// Problem constants
#define N_TOK 196
#define M_KV  23520      // (C/4)*N
#define EPSN  1e-3f
#define LOG2E 1.44269504088896340736f
#define NB    512        // persistent grid (co-resident: 4 waves, ~8KB LDS each)

// Workspace layout (in floats)
#define OFF_QC    0
#define OFF_KC    94080
#define OFF_VC    188160
#define OFF_ATTN  282240   // 480*480; becomes sim in-place; dead after phase THAT
#define OFF_THAT  512640   // 196*480
#define OFF_KV    606720   // float2[4*23520] = 188160 floats
#define OFF_SPART 794880   // 120*2 per-job [sum,sumsq] partials of attn
#define OFF_KPART 795200   // [4 stats][4 heads][96] = 1536 floats
#define OFF_SYNC  796800   // 8 unsigned counters (memset to 0 each launch)
// slabs alias the dead attn region (branch runs after that-GEMM)
#define CHUNKS 4
#define CH 5880            // 23520/4
#define OFF_LSLAB 282240   // 4*16*196 = 12544
#define OFF_CSLAB 294784   // 12544 (end 307328 < OFF_THAT)

__device__ __forceinline__ float fast_exp2(float x) {
#if __has_builtin(__builtin_amdgcn_exp2f)
    return __builtin_amdgcn_exp2f(x);
#else
    return exp2f(x);
#endif
}

// device-scope grid barrier: counter[phase] counts arrivals; release/acquire fences
__device__ __forceinline__ void gsync(unsigned* cnt, int phase) {
    __syncthreads();                       // waits vmcnt(0): block's stores are in L2
    if (threadIdx.x == 0) {
        __threadfence();                   // release: flush this XCD's L2
        __hip_atomic_fetch_add(cnt + phase, 1u, __ATOMIC_RELAXED, __HIP_MEMORY_SCOPE_AGENT);
        while (__hip_atomic_load(cnt + phase, __ATOMIC_RELAXED, __HIP_MEMORY_SCOPE_AGENT) < NB)
            __builtin_amdgcn_s_sleep(8);
        __threadfence();                   // acquire: invalidate stale lines
    }
    __syncthreads();
}

__global__ __launch_bounds__(256, 2) void k_fused(
        const float* __restrict__ emb1, const float* __restrict__ emb2,
        const float* __restrict__ emb3, const float* __restrict__ emb4,
        const float* __restrict__ embC,
        const float* __restrict__ WqC, const float* __restrict__ WkC, const float* __restrict__ WvC,
        const float* __restrict__ Wq1, const float* __restrict__ Wq2,
        const float* __restrict__ Wq3, const float* __restrict__ Wq4,
        const float* __restrict__ Wk,  const float* __restrict__ Wv,
        const float* __restrict__ Wo1, const float* __restrict__ Wo2,
        const float* __restrict__ Wo3, const float* __restrict__ Wo4,
        const float* __restrict__ g1,  const float* __restrict__ g2v,
        float* __restrict__ ws, float* __restrict__ out) {
    __shared__ float As[16][68];
    __shared__ float Bs[16][36];
    __shared__ float red[4][16];

    unsigned* cnt = (unsigned*)(ws + OFF_SYNC);
    const int bid = blockIdx.x;
    const int tid = threadIdx.x;
    const int wid = tid >> 6, lane = tid & 63;

    // ================= P0: Qc/Kc/Vc = emb_C @ W  (180 jobs) =================
    if (bid < 180) {
        int zi = bid / 60, rem = bid % 60;
        int m0 = (rem / 15) * 64, n0 = (rem % 15) * 32;
        const float* W = (zi == 0) ? WqC : (zi == 1 ? WkC : WvC);
        float* o = ws + zi * 94080;
        int ty = tid >> 4, tx = tid & 15;
        float a00=0,a01=0,a10=0,a11=0,a20=0,a21=0,a30=0,a31=0;
        int mrow = tid >> 2, kq = (tid & 3) * 4;
        for (int k0 = 0; k0 < 480; k0 += 16) {
            {
                int m = m0 + mrow;
                float4 v = make_float4(0,0,0,0);
                if (m < N_TOK) v = *(const float4*)(embC + m*480 + k0 + kq);
                As[kq+0][mrow] = v.x; As[kq+1][mrow] = v.y;
                As[kq+2][mrow] = v.z; As[kq+3][mrow] = v.w;
            }
            if (tid < 128) {
                int kk = tid >> 3, nq = (tid & 7) * 4;
                *(float4*)&Bs[kk][nq] = *(const float4*)(W + (k0+kk)*480 + n0 + nq);
            }
            __syncthreads();
            #pragma unroll
            for (int kk = 0; kk < 16; ++kk) {
                float4 av = *(const float4*)&As[kk][ty*4];
                float2 bv = *(const float2*)&Bs[kk][tx*2];
                a00 = fmaf(av.x, bv.x, a00); a01 = fmaf(av.x, bv.y, a01);
                a10 = fmaf(av.y, bv.x, a10); a11 = fmaf(av.y, bv.y, a11);
                a20 = fmaf(av.z, bv.x, a20); a21 = fmaf(av.z, bv.y, a21);
                a30 = fmaf(av.w, bv.x, a30); a31 = fmaf(av.w, bv.y, a31);
            }
            __syncthreads();
        }
        int m = m0 + ty*4, n = n0 + tx*2;
        if (m   < N_TOK) *(float2*)(o + (m  )*480 + n) = make_float2(a00, a01);
        if (m+1 < N_TOK) *(float2*)(o + (m+1)*480 + n) = make_float2(a10, a11);
        if (m+2 < N_TOK) *(float2*)(o + (m+2)*480 + n) = make_float2(a20, a21);
        if (m+3 < N_TOK) *(float2*)(o + (m+3)*480 + n) = make_float2(a30, a31);
    }
    gsync(cnt, 0);

    // ================= P1: attn = Qc^T @ Kc + stat partials (120 jobs) ======
    if (bid < 120) {
        const float* Qc = ws + OFF_QC;
        const float* Kc = ws + OFF_KC;
        float* attn = ws + OFF_ATTN;
        float* Spart = ws + OFF_SPART;
        int n0 = (bid % 15) * 32, m0 = (bid / 15) * 64;
        int ty = tid >> 4, tx = tid & 15;
        float a00=0,a01=0,a10=0,a11=0,a20=0,a21=0,a30=0,a31=0;
        for (int k0 = 0; k0 < 208; k0 += 16) {
            {
                int kk = tid >> 4, mq = (tid & 15) * 4;
                float4 v = make_float4(0,0,0,0);
                if (k0+kk < N_TOK && m0+mq < 480)
                    v = *(const float4*)(Qc + (k0+kk)*480 + m0 + mq);
                *(float4*)&As[kk][mq] = v;
            }
            if (tid < 128) {
                int kk = tid >> 3, nq = (tid & 7) * 4;
                float4 v = make_float4(0,0,0,0);
                if (k0+kk < N_TOK) v = *(const float4*)(Kc + (k0+kk)*480 + n0 + nq);
                *(float4*)&Bs[kk][nq] = v;
            }
            __syncthreads();
            #pragma unroll
            for (int kk = 0; kk < 16; ++kk) {
                float4 av = *(const float4*)&As[kk][ty*4];
                float2 bv = *(const float2*)&Bs[kk][tx*2];
                a00 = fmaf(av.x, bv.x, a00); a01 = fmaf(av.x, bv.y, a01);
                a10 = fmaf(av.y, bv.x, a10); a11 = fmaf(av.y, bv.y, a11);
                a20 = fmaf(av.z, bv.x, a20); a21 = fmaf(av.z, bv.y, a21);
                a30 = fmaf(av.w, bv.x, a30); a31 = fmaf(av.w, bv.y, a31);
            }
            __syncthreads();
        }
        int m = m0 + ty*4, n = n0 + tx*2;
        if (m   < 480) *(float2*)(attn + (m  )*480 + n) = make_float2(a00, a01);
        if (m+1 < 480) *(float2*)(attn + (m+1)*480 + n) = make_float2(a10, a11);
        if (m+2 < 480) *(float2*)(attn + (m+2)*480 + n) = make_float2(a20, a21);
        if (m+3 < 480) *(float2*)(attn + (m+3)*480 + n) = make_float2(a30, a31);
        float ls = a00+a01+a10+a11+a20+a21+a30+a31;
        float lq = a00*a00+a01*a01+a10*a10+a11*a11+a20*a20+a21*a21+a30*a30+a31*a31;
        #pragma unroll
        for (int o = 32; o > 0; o >>= 1) { ls += __shfl_xor(ls, o, 64); lq += __shfl_xor(lq, o, 64); }
        if (lane == 0) { red[wid][0] = ls; red[wid][1] = lq; }
        __syncthreads();
        if (tid == 0) {
            Spart[bid*2]   = red[0][0] + red[1][0] + red[2][0] + red[3][0];
            Spart[bid*2+1] = red[0][1] + red[1][1] + red[2][1] + red[3][1];
        }
    }
    gsync(cnt, 1);

    // ================= P2: per-row softmax of attn * s (480 jobs) ===========
    if (bid < 480) {
        float* attn = ws + OFF_ATTN;
        const float* Spart = ws + OFF_SPART;
        float ps = 0.f, pq = 0.f;
        if (tid < 120) { ps = Spart[tid*2]; pq = Spart[tid*2+1]; }
        #pragma unroll
        for (int o = 32; o > 0; o >>= 1) { ps += __shfl_xor(ps, o, 64); pq += __shfl_xor(pq, o, 64); }
        if (lane == 0) { red[wid][0] = ps; red[wid][1] = pq; }
        __syncthreads();
        float S  = red[0][0] + red[1][0] + red[2][0] + red[3][0];
        float SQ = red[0][1] + red[1][1] + red[2][1] + red[3][1];
        const float invCC = 1.f / (480.f * 480.f);
        float mean = S * invCC;
        float var  = SQ * invCC - mean * mean;
        float s = g1[0] * rsqrtf(var + EPSN);
        int c = bid;
        float y0 = attn[c * 480 + tid] * s;
        bool v1 = tid < 224;
        float y1 = v1 ? attn[c * 480 + tid + 256] * s : -INFINITY;
        float mx = fmaxf(y0, y1);
        #pragma unroll
        for (int o = 32; o > 0; o >>= 1) mx = fmaxf(mx, __shfl_xor(mx, o, 64));
        if (lane == 0) red[wid][2] = mx;
        __syncthreads();
        mx = fmaxf(fmaxf(red[0][2], red[1][2]), fmaxf(red[2][2], red[3][2]));
        float e0 = __expf(y0 - mx);
        float e1 = v1 ? __expf(y1 - mx) : 0.f;
        float sm = e0 + e1;
        #pragma unroll
        for (int o = 32; o > 0; o >>= 1) sm += __shfl_xor(sm, o, 64);
        if (lane == 0) red[wid][3] = sm;
        __syncthreads();
        sm = red[0][3] + red[1][3] + red[2][3] + red[3][3];
        float inv = 1.f / sm;
        attn[c * 480 + tid] = e0 * inv;
        if (v1) attn[c * 480 + tid + 256] = e1 * inv;
    }
    gsync(cnt, 2);

    // ================= P3: T_hat = Vc @ sim^T (60 jobs) =====================
    if (bid < 60) {
        const float* Vc = ws + OFF_VC;
        const float* sim = ws + OFF_ATTN;
        float* That = ws + OFF_THAT;
        int n0 = (bid % 15) * 32, m0 = (bid / 15) * 64;
        int ty = tid >> 4, tx = tid & 15;
        float a00=0,a01=0,a10=0,a11=0,a20=0,a21=0,a30=0,a31=0;
        int mrow = tid >> 2, kq = (tid & 3) * 4;
        for (int k0 = 0; k0 < 480; k0 += 16) {
            {
                int m = m0 + mrow;
                float4 v = make_float4(0,0,0,0);
                if (m < N_TOK) v = *(const float4*)(Vc + m*480 + k0 + kq);
                As[kq+0][mrow] = v.x; As[kq+1][mrow] = v.y;
                As[kq+2][mrow] = v.z; As[kq+3][mrow] = v.w;
            }
            if (tid < 128) {
                int nrow = tid >> 2, bkq = (tid & 3) * 4;
                float4 v = *(const float4*)(sim + (n0+nrow)*480 + k0 + bkq);
                Bs[bkq+0][nrow] = v.x; Bs[bkq+1][nrow] = v.y;
                Bs[bkq+2][nrow] = v.z; Bs[bkq+3][nrow] = v.w;
            }
            __syncthreads();
            #pragma unroll
            for (int kk = 0; kk < 16; ++kk) {
                float4 av = *(const float4*)&As[kk][ty*4];
                float2 bv = *(const float2*)&Bs[kk][tx*2];
                a00 = fmaf(av.x, bv.x, a00); a01 = fmaf(av.x, bv.y, a01);
                a10 = fmaf(av.y, bv.x, a10); a11 = fmaf(av.y, bv.y, a11);
                a20 = fmaf(av.z, bv.x, a20); a21 = fmaf(av.z, bv.y, a21);
                a30 = fmaf(av.w, bv.x, a30); a31 = fmaf(av.w, bv.y, a31);
            }
            __syncthreads();
        }
        int m = m0 + ty*4, n = n0 + tx*2;
        if (m   < N_TOK) *(float2*)(That + (m  )*480 + n) = make_float2(a00, a01);
        if (m+1 < N_TOK) *(float2*)(That + (m+1)*480 + n) = make_float2(a10, a11);
        if (m+2 < N_TOK) *(float2*)(That + (m+2)*480 + n) = make_float2(a20, a21);
        if (m+3 < N_TOK) *(float2*)(That + (m+3)*480 + n) = make_float2(a30, a31);
    }
    gsync(cnt, 3);

    // ================= P4: K/V projection + stat partials (92 jobs) =========
    if (bid < 92) {
        const float* That = ws + OFF_THAT;
        float2* KV = (float2*)(ws + OFF_KV);
        float* kpart = ws + OFF_KPART;
        int m = bid * 256 + tid;
        bool act = m < M_KV;
        int n = act ? (m % 196) : 0;
        int j = act ? (m / 196) : 0;
        float4 th = act ? *(const float4*)(That + n * 480 + 4 * j) : make_float4(0,0,0,0);
        #pragma unroll
        for (int h = 0; h < 4; ++h) {
            float kh = th.x * Wk[h] + th.y * Wk[4+h] + th.z * Wk[8+h] + th.w * Wk[12+h];
            float vh = th.x * Wv[h] + th.y * Wv[4+h] + th.z * Wv[8+h] + th.w * Wv[12+h];
            if (act) KV[h * M_KV + m] = make_float2(kh, vh);
            float su = act ? kh : 0.f;
            float sq = act ? kh * kh : 0.f;
            float mx = act ? kh : -INFINITY;
            float mn = act ? kh : INFINITY;
            #pragma unroll
            for (int o = 32; o > 0; o >>= 1) {
                su += __shfl_xor(su, o, 64);
                sq += __shfl_xor(sq, o, 64);
                mx = fmaxf(mx, __shfl_xor(mx, o, 64));
                mn = fminf(mn, __shfl_xor(mn, o, 64));
            }
            if (lane == 0) {
                red[wid][h*4+0] = su; red[wid][h*4+1] = sq;
                red[wid][h*4+2] = mx; red[wid][h*4+3] = mn;
            }
        }
        __syncthreads();
        if (tid < 16) {
            int h = tid & 3, st = tid >> 2;
            float v0 = red[0][h*4+st], v1 = red[1][h*4+st], v2 = red[2][h*4+st], v3 = red[3][h*4+st];
            float r;
            if (st < 2)       r = v0 + v1 + v2 + v3;
            else if (st == 2) r = fmaxf(fmaxf(v0, v1), fmaxf(v2, v3));
            else              r = fminf(fminf(v0, v1), fminf(v2, v3));
            kpart[st * 384 + h * 96 + bid] = r;
        }
    }
    gsync(cnt, 4);

    // ====== P5: branch attention + inline per-row stats (448 jobs) ==========
    // job -> (qg, row, chunk); per block: derive row stats, then exp-reduce
    if (bid < 448) {
        const float2* KV = (const float2*)(ws + OFF_KV);
        const float* kpart = ws + OFF_KPART;
        float* Lslab = ws + OFF_LSLAB;
        float* Cslab = ws + OFF_CSLAB;
        int qg = bid % 7, row = (bid / 7) % 16, chunk = bid / 112;
        int i = row >> 2, h = row & 3;
        const float* emb = (i == 0) ? emb1 : (i == 1) ? emb2 : (i == 2) ? emb3 : emb4;
        const float* Wq  = (i == 0) ? Wq1 : (i == 1) ? Wq2 : (i == 2) ? Wq3 : Wq4;
        // --- row stats (redundant per block; tiny) ---
        bool actq = tid < 196;
        float Q = 0.f;
        if (actq) {
            Q = emb[tid*4]*Wq[h] + emb[tid*4+1]*Wq[4+h] +
                emb[tid*4+2]*Wq[8+h] + emb[tid*4+3]*Wq[12+h];
        }
        float s = actq ? Q : 0.f, s2 = actq ? Q*Q : 0.f;
        float ks = 0.f, kq2 = 0.f, km = -INFINITY, kn = INFINITY;
        if (tid < 92) {
            ks  = kpart[0*384 + h*96 + tid];
            kq2 = kpart[1*384 + h*96 + tid];
            km  = kpart[2*384 + h*96 + tid];
            kn  = kpart[3*384 + h*96 + tid];
        }
        #pragma unroll
        for (int o = 32; o > 0; o >>= 1) {
            s += __shfl_xor(s, o, 64); s2 += __shfl_xor(s2, o, 64);
            ks += __shfl_xor(ks, o, 64); kq2 += __shfl_xor(kq2, o, 64);
            km = fmaxf(km, __shfl_xor(km, o, 64)); kn = fminf(kn, __shfl_xor(kn, o, 64));
        }
        if (lane == 0) {
            red[wid][0] = s;  red[wid][1] = s2; red[wid][2] = ks;
            red[wid][3] = kq2; red[wid][4] = km; red[wid][5] = kn;
        }
        __syncthreads();
        float sumQ  = red[0][0] + red[1][0] + red[2][0] + red[3][0];
        float sumQ2 = red[0][1] + red[1][1] + red[2][1] + red[3][1];
        float Ksum  = red[0][2] + red[1][2] + red[2][2] + red[3][2];
        float Ksq   = red[0][3] + red[1][3] + red[2][3] + red[3][3];
        float Kmax  = fmaxf(fmaxf(red[0][4], red[1][4]), fmaxf(red[2][4], red[3][4]));
        float Kmin  = fminf(fminf(red[0][5], red[1][5]), fminf(red[2][5], red[3][5]));
        float Qbar = sumQ * (1.f/196.f), Q2bar = sumQ2 * (1.f/196.f);
        float Kbar = Ksum * (1.f/(float)M_KV), K2bar = Ksq * (1.f/(float)M_KV);
        float mu = Qbar * Kbar;
        float var = Q2bar * K2bar - mu * mu;
        float sc = g2v[h] * rsqrtf(var + EPSN);
        // --- per-wave 7 q's: beta (log2e-folded) and analytic row max ---
        int qbase = qg * 28 + wid * 7;
        float B2[7], nM2[7];
        #pragma unroll
        for (int j = 0; j < 7; ++j) {
            int q = qbase + j;
            float Qj = emb[q*4]*Wq[h] + emb[q*4+1]*Wq[4+h] +
                       emb[q*4+2]*Wq[8+h] + emb[q*4+3]*Wq[12+h];
            float b = Qj * sc;
            float M = (b >= 0.f) ? b * Kmax : b * Kmin;
            B2[j]  = b * LOG2E;
            nM2[j] = -M * LOG2E;
        }
        // --- split-k exp reduction over this chunk ---
        const float2* kvp = KV + h * M_KV;
        int kbase = chunk * CH, kend = kbase + CH;
        float l[7] = {0,0,0,0,0,0,0};
        float a[7] = {0,0,0,0,0,0,0};
        for (int k = kbase + lane; k < kend; k += 64) {
            float2 p = kvp[k];
            #pragma unroll
            for (int j = 0; j < 7; ++j) {
                float x = fast_exp2(fmaf(B2[j], p.x, nM2[j]));
                l[j] += x;
                a[j] = fmaf(x, p.y, a[j]);
            }
        }
        int sbase = (chunk * 16 + row) * 196 + qbase;
        #pragma unroll
        for (int j = 0; j < 7; ++j) {
            float lv = l[j], av = a[j];
            #pragma unroll
            for (int o = 32; o > 0; o >>= 1) { lv += __shfl_xor(lv, o, 64); av += __shfl_xor(av, o, 64); }
            if (lane == 0) {
                Lslab[sbase + j] = lv;
                Cslab[sbase + j] = av;
            }
        }
    }
    gsync(cnt, 5);

    // ================= P6: finalize (4 jobs) ================================
    if (bid < 4) {
        const float* Lslab = ws + OFF_LSLAB;
        const float* Cslab = ws + OFF_CSLAB;
        int i = bid;
        int q = tid;
        if (q < 196) {
            const float* Wo = (i == 0) ? Wo1 : (i == 1) ? Wo2 : (i == 2) ? Wo3 : Wo4;
            float c[4];
            #pragma unroll
            for (int h = 0; h < 4; ++h) {
                float L = 0.f, Cc = 0.f;
                #pragma unroll
                for (int ch = 0; ch < CHUNKS; ++ch) {
                    int idx = (ch * 16 + i * 4 + h) * 196 + q;
                    L  += Lslab[idx];
                    Cc += Cslab[idx];
                }
                c[h] = Cc / L;
            }
            float4 o;
            o.x = c[0]*Wo[0] + c[1]*Wo[4] + c[2]*Wo[8]  + c[3]*Wo[12];
            o.y = c[0]*Wo[1] + c[1]*Wo[5] + c[2]*Wo[9]  + c[3]*Wo[13];
            o.z = c[0]*Wo[2] + c[1]*Wo[6] + c[2]*Wo[10] + c[3]*Wo[14];
            o.w = c[0]*Wo[3] + c[1]*Wo[7] + c[2]*Wo[11] + c[3]*Wo[15];
            *(float4*)(out + i * 784 + q * 4) = o;
        }
    }
}

extern "C" void kernel_launch(void* const* d_in, const int* in_sizes, int n_in,
                              void* d_out, int out_size, void* d_ws, size_t ws_size,
                              hipStream_t stream) {
    const float* emb1 = (const float*)d_in[0];
    const float* emb2 = (const float*)d_in[1];
    const float* emb3 = (const float*)d_in[2];
    const float* emb4 = (const float*)d_in[3];
    const float* embC = (const float*)d_in[4];
    const float* WqC  = (const float*)d_in[5];
    const float* WkC  = (const float*)d_in[6];
    const float* WvC  = (const float*)d_in[7];
    const float* Wq1  = (const float*)d_in[8];
    const float* Wq2  = (const float*)d_in[9];
    const float* Wq3  = (const float*)d_in[10];
    const float* Wq4  = (const float*)d_in[11];
    const float* Wk   = (const float*)d_in[12];
    const float* Wv   = (const float*)d_in[13];
    const float* Wo1  = (const float*)d_in[14];
    const float* Wo2  = (const float*)d_in[15];
    const float* Wo3  = (const float*)d_in[16];
    const float* Wo4  = (const float*)d_in[17];
    const float* g1   = (const float*)d_in[18];
    const float* g2   = (const float*)d_in[20];
    float* ws = (float*)d_ws;
    float* out = (float*)d_out;

    // zero the 8 barrier counters (32 B) — counters must start at 0 each call
    hipMemsetAsync(ws + OFF_SYNC, 0, 8 * sizeof(unsigned), stream);

    k_fused<<<NB, 256, 0, stream>>>(emb1, emb2, emb3, emb4, embC,
                                    WqC, WkC, WvC,
                                    Wq1, Wq2, Wq3, Wq4, Wk, Wv,
                                    Wo1, Wo2, Wo3, Wo4, g1, g2, ws, out);
}

// Round 6
// 184.035 us; speedup vs baseline: 1.9489x; 1.9489x over previous
//
#include <hip/hip_runtime.h>
#include <hip/hip_bf16.h>
#include <math.h>

// Problem constants
#define N_TOK 196
#define M_KV  23520      // (C/4)*N
#define EPSN  1e-3f
#define LOG2E 1.44269504088896340736f
#define NB    512        // persistent grid: 32 groups x 16

// Workspace layout (in floats)
#define OFF_QC    0
#define OFF_KC    94080
#define OFF_VC    188160
#define OFF_ATTN  282240   // 480*480; sim in-place; dead after P3
#define OFF_KV    606720   // float2[4*23520] = 188160 floats (end 794880)
#define OFF_SPART 794880   // 120*2 psi1 partials
#define OFF_KPART 795200   // [4 stats][4 heads][64 slots] = 1024 floats
#define OFF_SYNC  796800   // 256 unsigned: grp[5][32] | glob[5] | go[5*16]
// slabs alias dead attn region (written in P4, after P3 consumed sim)
#define CHUNKS 4
#define CH 5880            // 23520/4
#define OFF_LSLAB 282240   // 4*16*196 = 12544
#define OFF_CSLAB 294784   // 12544 (end 307328)

__device__ __forceinline__ float fast_exp2(float x) {
#if __has_builtin(__builtin_amdgcn_exp2f)
    return __builtin_amdgcn_exp2f(x);
#else
    return exp2f(x);
#endif
}

// Tree grid-barrier: per-group counters -> global counter -> write-once go flag.
// Avoids 512 same-line RMWs and avoids polling a line under RMW traffic.
__device__ __forceinline__ void gsync(unsigned* sy, int phase, int bid) {
    __syncthreads();
    if (threadIdx.x == 0) {
        __builtin_amdgcn_fence(__ATOMIC_RELEASE, "agent");
        unsigned* grp  = sy + phase * 32 + (bid >> 4);
        unsigned* glob = sy + 160 + phase;
        unsigned* go   = sy + 176 + phase * 16;
        if (__hip_atomic_fetch_add(grp, 1u, __ATOMIC_RELAXED, __HIP_MEMORY_SCOPE_AGENT) == 15u) {
            if (__hip_atomic_fetch_add(glob, 1u, __ATOMIC_RELAXED, __HIP_MEMORY_SCOPE_AGENT) == 31u) {
                __hip_atomic_store(go, 1u, __ATOMIC_RELAXED, __HIP_MEMORY_SCOPE_AGENT);
            }
        }
        int it = 0;
        while (__hip_atomic_load(go, __ATOMIC_RELAXED, __HIP_MEMORY_SCOPE_AGENT) == 0u) {
            if (it < 2)      __builtin_amdgcn_s_sleep(1);
            else if (it < 4) __builtin_amdgcn_s_sleep(4);
            else if (it < 8) __builtin_amdgcn_s_sleep(16);
            else             __builtin_amdgcn_s_sleep(32);
            ++it;
        }
        __builtin_amdgcn_fence(__ATOMIC_ACQUIRE, "agent");
    }
    __syncthreads();
}

__global__ __launch_bounds__(256, 2) void k_fused(
        const float* __restrict__ emb1, const float* __restrict__ emb2,
        const float* __restrict__ emb3, const float* __restrict__ emb4,
        const float* __restrict__ embC,
        const float* __restrict__ WqC, const float* __restrict__ WkC, const float* __restrict__ WvC,
        const float* __restrict__ Wq1, const float* __restrict__ Wq2,
        const float* __restrict__ Wq3, const float* __restrict__ Wq4,
        const float* __restrict__ Wk,  const float* __restrict__ Wv,
        const float* __restrict__ Wo1, const float* __restrict__ Wo2,
        const float* __restrict__ Wo3, const float* __restrict__ Wo4,
        const float* __restrict__ g1,  const float* __restrict__ g2v,
        float* __restrict__ ws, float* __restrict__ out) {
    __shared__ float As[16][68];
    __shared__ float Bs[16][36];
    __shared__ float red[4][16];
    __shared__ float Tile[64][33];   // P3: That tile staging for KV projection

    unsigned* sy = (unsigned*)(ws + OFF_SYNC);
    const int bid = blockIdx.x;
    const int tid = threadIdx.x;
    const int wid = tid >> 6, lane = tid & 63;

    // ================= P0: Qc/Kc/Vc = emb_C @ W  (180 jobs) =================
    if (bid < 180) {
        int zi = bid / 60, rem = bid % 60;
        int m0 = (rem / 15) * 64, n0 = (rem % 15) * 32;
        const float* W = (zi == 0) ? WqC : (zi == 1 ? WkC : WvC);
        float* o = ws + zi * 94080;
        int ty = tid >> 4, tx = tid & 15;
        float a00=0,a01=0,a10=0,a11=0,a20=0,a21=0,a30=0,a31=0;
        int mrow = tid >> 2, kq = (tid & 3) * 4;
        for (int k0 = 0; k0 < 480; k0 += 16) {
            {
                int m = m0 + mrow;
                float4 v = make_float4(0,0,0,0);
                if (m < N_TOK) v = *(const float4*)(embC + m*480 + k0 + kq);
                As[kq+0][mrow] = v.x; As[kq+1][mrow] = v.y;
                As[kq+2][mrow] = v.z; As[kq+3][mrow] = v.w;
            }
            if (tid < 128) {
                int kk = tid >> 3, nq = (tid & 7) * 4;
                *(float4*)&Bs[kk][nq] = *(const float4*)(W + (k0+kk)*480 + n0 + nq);
            }
            __syncthreads();
            #pragma unroll
            for (int kk = 0; kk < 16; ++kk) {
                float4 av = *(const float4*)&As[kk][ty*4];
                float2 bv = *(const float2*)&Bs[kk][tx*2];
                a00 = fmaf(av.x, bv.x, a00); a01 = fmaf(av.x, bv.y, a01);
                a10 = fmaf(av.y, bv.x, a10); a11 = fmaf(av.y, bv.y, a11);
                a20 = fmaf(av.z, bv.x, a20); a21 = fmaf(av.z, bv.y, a21);
                a30 = fmaf(av.w, bv.x, a30); a31 = fmaf(av.w, bv.y, a31);
            }
            __syncthreads();
        }
        int m = m0 + ty*4, n = n0 + tx*2;
        if (m   < N_TOK) *(float2*)(o + (m  )*480 + n) = make_float2(a00, a01);
        if (m+1 < N_TOK) *(float2*)(o + (m+1)*480 + n) = make_float2(a10, a11);
        if (m+2 < N_TOK) *(float2*)(o + (m+2)*480 + n) = make_float2(a20, a21);
        if (m+3 < N_TOK) *(float2*)(o + (m+3)*480 + n) = make_float2(a30, a31);
    }
    gsync(sy, 0, bid);

    // ================= P1: attn = Qc^T @ Kc + stat partials (120 jobs) ======
    if (bid < 120) {
        const float* Qc = ws + OFF_QC;
        const float* Kc = ws + OFF_KC;
        float* attn = ws + OFF_ATTN;
        float* Spart = ws + OFF_SPART;
        int n0 = (bid % 15) * 32, m0 = (bid / 15) * 64;
        int ty = tid >> 4, tx = tid & 15;
        float a00=0,a01=0,a10=0,a11=0,a20=0,a21=0,a30=0,a31=0;
        for (int k0 = 0; k0 < 208; k0 += 16) {
            {
                int kk = tid >> 4, mq = (tid & 15) * 4;
                float4 v = make_float4(0,0,0,0);
                if (k0+kk < N_TOK && m0+mq < 480)
                    v = *(const float4*)(Qc + (k0+kk)*480 + m0 + mq);
                *(float4*)&As[kk][mq] = v;
            }
            if (tid < 128) {
                int kk = tid >> 3, nq = (tid & 7) * 4;
                float4 v = make_float4(0,0,0,0);
                if (k0+kk < N_TOK) v = *(const float4*)(Kc + (k0+kk)*480 + n0 + nq);
                *(float4*)&Bs[kk][nq] = v;
            }
            __syncthreads();
            #pragma unroll
            for (int kk = 0; kk < 16; ++kk) {
                float4 av = *(const float4*)&As[kk][ty*4];
                float2 bv = *(const float2*)&Bs[kk][tx*2];
                a00 = fmaf(av.x, bv.x, a00); a01 = fmaf(av.x, bv.y, a01);
                a10 = fmaf(av.y, bv.x, a10); a11 = fmaf(av.y, bv.y, a11);
                a20 = fmaf(av.z, bv.x, a20); a21 = fmaf(av.z, bv.y, a21);
                a30 = fmaf(av.w, bv.x, a30); a31 = fmaf(av.w, bv.y, a31);
            }
            __syncthreads();
        }
        int m = m0 + ty*4, n = n0 + tx*2;
        if (m   < 480) *(float2*)(attn + (m  )*480 + n) = make_float2(a00, a01);
        if (m+1 < 480) *(float2*)(attn + (m+1)*480 + n) = make_float2(a10, a11);
        if (m+2 < 480) *(float2*)(attn + (m+2)*480 + n) = make_float2(a20, a21);
        if (m+3 < 480) *(float2*)(attn + (m+3)*480 + n) = make_float2(a30, a31);
        float ls = a00+a01+a10+a11+a20+a21+a30+a31;
        float lq = a00*a00+a01*a01+a10*a10+a11*a11+a20*a20+a21*a21+a30*a30+a31*a31;
        #pragma unroll
        for (int o = 32; o > 0; o >>= 1) { ls += __shfl_xor(ls, o, 64); lq += __shfl_xor(lq, o, 64); }
        if (lane == 0) { red[wid][0] = ls; red[wid][1] = lq; }
        __syncthreads();
        if (tid == 0) {
            Spart[bid*2]   = red[0][0] + red[1][0] + red[2][0] + red[3][0];
            Spart[bid*2+1] = red[0][1] + red[1][1] + red[2][1] + red[3][1];
        }
    }
    gsync(sy, 1, bid);

    // ================= P2: per-row softmax of attn * s (480 jobs) ===========
    if (bid < 480) {
        float* attn = ws + OFF_ATTN;
        const float* Spart = ws + OFF_SPART;
        float ps = 0.f, pq = 0.f;
        if (tid < 120) { ps = Spart[tid*2]; pq = Spart[tid*2+1]; }
        #pragma unroll
        for (int o = 32; o > 0; o >>= 1) { ps += __shfl_xor(ps, o, 64); pq += __shfl_xor(pq, o, 64); }
        if (lane == 0) { red[wid][0] = ps; red[wid][1] = pq; }
        __syncthreads();
        float S  = red[0][0] + red[1][0] + red[2][0] + red[3][0];
        float SQ = red[0][1] + red[1][1] + red[2][1] + red[3][1];
        const float invCC = 1.f / (480.f * 480.f);
        float mean = S * invCC;
        float var  = SQ * invCC - mean * mean;
        float s = g1[0] * rsqrtf(var + EPSN);
        int c = bid;
        float y0 = attn[c * 480 + tid] * s;
        bool v1 = tid < 224;
        float y1 = v1 ? attn[c * 480 + tid + 256] * s : -INFINITY;
        float mx = fmaxf(y0, y1);
        #pragma unroll
        for (int o = 32; o > 0; o >>= 1) mx = fmaxf(mx, __shfl_xor(mx, o, 64));
        if (lane == 0) red[wid][2] = mx;
        __syncthreads();
        mx = fmaxf(fmaxf(red[0][2], red[1][2]), fmaxf(red[2][2], red[3][2]));
        float e0 = __expf(y0 - mx);
        float e1 = v1 ? __expf(y1 - mx) : 0.f;
        float sm = e0 + e1;
        #pragma unroll
        for (int o = 32; o > 0; o >>= 1) sm += __shfl_xor(sm, o, 64);
        if (lane == 0) red[wid][3] = sm;
        __syncthreads();
        sm = red[0][3] + red[1][3] + red[2][3] + red[3][3];
        float inv = 1.f / sm;
        attn[c * 480 + tid] = e0 * inv;
        if (v1) attn[c * 480 + tid + 256] = e1 * inv;
    }
    gsync(sy, 2, bid);

    // ====== P3: T_hat tile GEMM fused with K/V projection + kpart (60 jobs) =
    if (bid < 60) {
        const float* Vc = ws + OFF_VC;
        const float* sim = ws + OFF_ATTN;
        float2* KV = (float2*)(ws + OFF_KV);
        float* kpart = ws + OFF_KPART;
        int n0 = (bid % 15) * 32, m0 = (bid / 15) * 64;
        int ty = tid >> 4, tx = tid & 15;
        float a00=0,a01=0,a10=0,a11=0,a20=0,a21=0,a30=0,a31=0;
        int mrow = tid >> 2, kq = (tid & 3) * 4;
        for (int k0 = 0; k0 < 480; k0 += 16) {
            {
                int m = m0 + mrow;
                float4 v = make_float4(0,0,0,0);
                if (m < N_TOK) v = *(const float4*)(Vc + m*480 + k0 + kq);
                As[kq+0][mrow] = v.x; As[kq+1][mrow] = v.y;
                As[kq+2][mrow] = v.z; As[kq+3][mrow] = v.w;
            }
            if (tid < 128) {
                int nrow = tid >> 2, bkq = (tid & 3) * 4;
                float4 v = *(const float4*)(sim + (n0+nrow)*480 + k0 + bkq);
                Bs[bkq+0][nrow] = v.x; Bs[bkq+1][nrow] = v.y;
                Bs[bkq+2][nrow] = v.z; Bs[bkq+3][nrow] = v.w;
            }
            __syncthreads();
            #pragma unroll
            for (int kk = 0; kk < 16; ++kk) {
                float4 av = *(const float4*)&As[kk][ty*4];
                float2 bv = *(const float2*)&Bs[kk][tx*2];
                a00 = fmaf(av.x, bv.x, a00); a01 = fmaf(av.x, bv.y, a01);
                a10 = fmaf(av.y, bv.x, a10); a11 = fmaf(av.y, bv.y, a11);
                a20 = fmaf(av.z, bv.x, a20); a21 = fmaf(av.z, bv.y, a21);
                a30 = fmaf(av.w, bv.x, a30); a31 = fmaf(av.w, bv.y, a31);
            }
            __syncthreads();
        }
        // stage tile (phantom rows hold exact zeros)
        int r0 = ty*4, cc = tx*2;
        Tile[r0+0][cc] = a00; Tile[r0+0][cc+1] = a01;
        Tile[r0+1][cc] = a10; Tile[r0+1][cc+1] = a11;
        Tile[r0+2][cc] = a20; Tile[r0+2][cc+1] = a21;
        Tile[r0+3][cc] = a30; Tile[r0+3][cc+1] = a31;
        __syncthreads();
        // K/V projection + per-block stats over this tile's 64x8 (token,j) entries
        float su[4] = {0,0,0,0}, sq[4] = {0,0,0,0};
        float mx[4] = {-INFINITY,-INFINITY,-INFINITY,-INFINITY};
        float mn[4] = { INFINITY, INFINITY, INFINITY, INFINITY};
        #pragma unroll
        for (int rep = 0; rep < 2; ++rep) {
            int e = tid + rep * 256;
            int t = e >> 3, jj = e & 7;
            int tok = m0 + t;
            bool act = tok < N_TOK;
            float c0 = Tile[t][4*jj], c1 = Tile[t][4*jj+1];
            float c2 = Tile[t][4*jj+2], c3 = Tile[t][4*jj+3];
            int m_kv = (n0/4 + jj) * 196 + tok;
            #pragma unroll
            for (int h = 0; h < 4; ++h) {
                float kh = c0*Wk[h] + c1*Wk[4+h] + c2*Wk[8+h] + c3*Wk[12+h];
                float vh = c0*Wv[h] + c1*Wv[4+h] + c2*Wv[8+h] + c3*Wv[12+h];
                if (act) {
                    KV[h * M_KV + m_kv] = make_float2(kh, vh);
                    su[h] += kh; sq[h] += kh * kh;
                    mx[h] = fmaxf(mx[h], kh); mn[h] = fminf(mn[h], kh);
                }
            }
        }
        #pragma unroll
        for (int h = 0; h < 4; ++h) {
            #pragma unroll
            for (int o = 32; o > 0; o >>= 1) {
                su[h] += __shfl_xor(su[h], o, 64);
                sq[h] += __shfl_xor(sq[h], o, 64);
                mx[h] = fmaxf(mx[h], __shfl_xor(mx[h], o, 64));
                mn[h] = fminf(mn[h], __shfl_xor(mn[h], o, 64));
            }
            if (lane == 0) {
                red[wid][h*4+0] = su[h]; red[wid][h*4+1] = sq[h];
                red[wid][h*4+2] = mx[h]; red[wid][h*4+3] = mn[h];
            }
        }
        __syncthreads();
        if (tid < 16) {
            int h = tid & 3, st = tid >> 2;
            float v0 = red[0][h*4+st], v1 = red[1][h*4+st], v2 = red[2][h*4+st], v3 = red[3][h*4+st];
            float r;
            if (st < 2)       r = v0 + v1 + v2 + v3;
            else if (st == 2) r = fmaxf(fmaxf(v0, v1), fmaxf(v2, v3));
            else              r = fminf(fminf(v0, v1), fminf(v2, v3));
            kpart[st * 256 + h * 64 + bid] = r;
        }
    }
    gsync(sy, 3, bid);

    // ====== P4: branch attention + inline per-row stats (448 jobs) ==========
    if (bid < 448) {
        const float2* KV = (const float2*)(ws + OFF_KV);
        const float* kpart = ws + OFF_KPART;
        float* Lslab = ws + OFF_LSLAB;
        float* Cslab = ws + OFF_CSLAB;
        int qg = bid % 7, row = (bid / 7) % 16, chunk = bid / 112;
        int i = row >> 2, h = row & 3;
        const float* emb = (i == 0) ? emb1 : (i == 1) ? emb2 : (i == 2) ? emb3 : emb4;
        const float* Wq  = (i == 0) ? Wq1 : (i == 1) ? Wq2 : (i == 2) ? Wq3 : Wq4;
        bool actq = tid < 196;
        float Q = 0.f;
        if (actq) {
            Q = emb[tid*4]*Wq[h] + emb[tid*4+1]*Wq[4+h] +
                emb[tid*4+2]*Wq[8+h] + emb[tid*4+3]*Wq[12+h];
        }
        float s = actq ? Q : 0.f, s2 = actq ? Q*Q : 0.f;
        float ks = 0.f, kq2 = 0.f, km = -INFINITY, kn = INFINITY;
        if (tid < 60) {
            ks  = kpart[0*256 + h*64 + tid];
            kq2 = kpart[1*256 + h*64 + tid];
            km  = kpart[2*256 + h*64 + tid];
            kn  = kpart[3*256 + h*64 + tid];
        }
        #pragma unroll
        for (int o = 32; o > 0; o >>= 1) {
            s += __shfl_xor(s, o, 64); s2 += __shfl_xor(s2, o, 64);
            ks += __shfl_xor(ks, o, 64); kq2 += __shfl_xor(kq2, o, 64);
            km = fmaxf(km, __shfl_xor(km, o, 64)); kn = fminf(kn, __shfl_xor(kn, o, 64));
        }
        if (lane == 0) {
            red[wid][0] = s;  red[wid][1] = s2; red[wid][2] = ks;
            red[wid][3] = kq2; red[wid][4] = km; red[wid][5] = kn;
        }
        __syncthreads();
        float sumQ  = red[0][0] + red[1][0] + red[2][0] + red[3][0];
        float sumQ2 = red[0][1] + red[1][1] + red[2][1] + red[3][1];
        float Ksum  = red[0][2] + red[1][2] + red[2][2] + red[3][2];
        float Ksq   = red[0][3] + red[1][3] + red[2][3] + red[3][3];
        float Kmax  = fmaxf(fmaxf(red[0][4], red[1][4]), fmaxf(red[2][4], red[3][4]));
        float Kmin  = fminf(fminf(red[0][5], red[1][5]), fminf(red[2][5], red[3][5]));
        float Qbar = sumQ * (1.f/196.f), Q2bar = sumQ2 * (1.f/196.f);
        float Kbar = Ksum * (1.f/(float)M_KV), K2bar = Ksq * (1.f/(float)M_KV);
        float mu = Qbar * Kbar;
        float var = Q2bar * K2bar - mu * mu;
        float sc = g2v[h] * rsqrtf(var + EPSN);
        int qbase = qg * 28 + wid * 7;
        float B2[7], nM2[7];
        #pragma unroll
        for (int j = 0; j < 7; ++j) {
            int q = qbase + j;
            float Qj = emb[q*4]*Wq[h] + emb[q*4+1]*Wq[4+h] +
                       emb[q*4+2]*Wq[8+h] + emb[q*4+3]*Wq[12+h];
            float b = Qj * sc;
            float M = (b >= 0.f) ? b * Kmax : b * Kmin;
            B2[j]  = b * LOG2E;
            nM2[j] = -M * LOG2E;
        }
        const float2* kvp = KV + h * M_KV;
        int kbase = chunk * CH, kend = kbase + CH;
        float l[7] = {0,0,0,0,0,0,0};
        float a[7] = {0,0,0,0,0,0,0};
        for (int k = kbase + lane; k < kend; k += 64) {
            float2 p = kvp[k];
            #pragma unroll
            for (int j = 0; j < 7; ++j) {
                float x = fast_exp2(fmaf(B2[j], p.x, nM2[j]));
                l[j] += x;
                a[j] = fmaf(x, p.y, a[j]);
            }
        }
        int sbase = (chunk * 16 + row) * 196 + qbase;
        #pragma unroll
        for (int j = 0; j < 7; ++j) {
            float lv = l[j], av = a[j];
            #pragma unroll
            for (int o = 32; o > 0; o >>= 1) { lv += __shfl_xor(lv, o, 64); av += __shfl_xor(av, o, 64); }
            if (lane == 0) {
                Lslab[sbase + j] = lv;
                Cslab[sbase + j] = av;
            }
        }
    }
    gsync(sy, 4, bid);

    // ================= P5: finalize (4 jobs) ================================
    if (bid < 4) {
        const float* Lslab = ws + OFF_LSLAB;
        const float* Cslab = ws + OFF_CSLAB;
        int i = bid;
        int q = tid;
        if (q < 196) {
            const float* Wo = (i == 0) ? Wo1 : (i == 1) ? Wo2 : (i == 2) ? Wo3 : Wo4;
            float c[4];
            #pragma unroll
            for (int h = 0; h < 4; ++h) {
                float L = 0.f, Cc = 0.f;
                #pragma unroll
                for (int ch = 0; ch < CHUNKS; ++ch) {
                    int idx = (ch * 16 + i * 4 + h) * 196 + q;
                    L  += Lslab[idx];
                    Cc += Cslab[idx];
                }
                c[h] = Cc / L;
            }
            float4 o;
            o.x = c[0]*Wo[0] + c[1]*Wo[4] + c[2]*Wo[8]  + c[3]*Wo[12];
            o.y = c[0]*Wo[1] + c[1]*Wo[5] + c[2]*Wo[9]  + c[3]*Wo[13];
            o.z = c[0]*Wo[2] + c[1]*Wo[6] + c[2]*Wo[10] + c[3]*Wo[14];
            o.w = c[0]*Wo[3] + c[1]*Wo[7] + c[2]*Wo[11] + c[3]*Wo[15];
            *(float4*)(out + i * 784 + q * 4) = o;
        }
    }
}

extern "C" void kernel_launch(void* const* d_in, const int* in_sizes, int n_in,
                              void* d_out, int out_size, void* d_ws, size_t ws_size,
                              hipStream_t stream) {
    const float* emb1 = (const float*)d_in[0];
    const float* emb2 = (const float*)d_in[1];
    const float* emb3 = (const float*)d_in[2];
    const float* emb4 = (const float*)d_in[3];
    const float* embC = (const float*)d_in[4];
    const float* WqC  = (const float*)d_in[5];
    const float* WkC  = (const float*)d_in[6];
    const float* WvC  = (const float*)d_in[7];
    const float* Wq1  = (const float*)d_in[8];
    const float* Wq2  = (const float*)d_in[9];
    const float* Wq3  = (const float*)d_in[10];
    const float* Wq4  = (const float*)d_in[11];
    const float* Wk   = (const float*)d_in[12];
    const float* Wv   = (const float*)d_in[13];
    const float* Wo1  = (const float*)d_in[14];
    const float* Wo2  = (const float*)d_in[15];
    const float* Wo3  = (const float*)d_in[16];
    const float* Wo4  = (const float*)d_in[17];
    const float* g1   = (const float*)d_in[18];
    const float* g2   = (const float*)d_in[20];
    float* ws = (float*)d_ws;
    float* out = (float*)d_out;

    // zero barrier state (grp/glob/go) each call
    hipMemsetAsync(ws + OFF_SYNC, 0, 256 * sizeof(unsigned), stream);

    k_fused<<<NB, 256, 0, stream>>>(emb1, emb2, emb3, emb4, embC,
                                    WqC, WkC, WvC,
                                    Wq1, Wq2, Wq3, Wq4, Wk, Wv,
                                    Wo1, Wo2, Wo3, Wo4, g1, g2, ws, out);
}

// Round 7
// 80.297 us; speedup vs baseline: 4.4668x; 2.2919x over previous
//
#include <hip/hip_runtime.h>
#include <hip/hip_bf16.h>
#include <math.h>

// Problem constants
#define N_TOK 196
#define M_KV  23520      // (C/4)*N
#define EPSN  1e-3f
#define LOG2E 1.44269504088896340736f

// Workspace layout (in floats), total 752256 (< 807442 used in round 1 -> fits)
#define OFF_QC    0
#define OFF_KC    94080
#define OFF_VC    188160
#define OFF_ATTN  282240   // 480*480 raw attn scores (psi1 pre-norm)
#define OFF_KV    512640   // float2[4*23520] = 188160 floats
#define OFF_SPART 700800   // 120*2 psi1 [sum,sumsq] per-block partials
#define OFF_KPART 701056   // [4 stats][4 heads][64 slots] = 1024 floats
#define OFF_LSLAB 702080   // 8*16*196 = 25088
#define OFF_CSLAB 727168   // 25088 (end 752256)
#define CHUNKS 8
#define CH 2940            // 23520/8

__device__ __forceinline__ float fast_exp2(float x) {
#if __has_builtin(__builtin_amdgcn_exp2f)
    return __builtin_amdgcn_exp2f(x);
#else
    return exp2f(x);
#endif
}

#define GEMM_COMPUTE(AS, BS) \
    _Pragma("unroll") \
    for (int kk2 = 0; kk2 < 16; ++kk2) { \
        float4 av = *(const float4*)&AS[kk2][ty*4]; \
        float2 bv = *(const float2*)&BS[kk2][tx*2]; \
        a00 = fmaf(av.x, bv.x, a00); a01 = fmaf(av.x, bv.y, a01); \
        a10 = fmaf(av.y, bv.x, a10); a11 = fmaf(av.y, bv.y, a11); \
        a20 = fmaf(av.z, bv.x, a20); a21 = fmaf(av.z, bv.y, a21); \
        a30 = fmaf(av.w, bv.x, a30); a31 = fmaf(av.w, bv.y, a31); \
    }

// ---------------- K1: Qc/Kc/Vc = emb_C @ W  (180 blocks) --------------------
// 64x32 tile, K=480 (30 steps), register-prefetch double-buffered LDS.
__global__ __launch_bounds__(256) void k_qkv(const float* __restrict__ embC,
                                             const float* __restrict__ Wq,
                                             const float* __restrict__ Wk,
                                             const float* __restrict__ Wv,
                                             float* __restrict__ ws) {
    int bid = blockIdx.x;
    int zi = bid / 60, rem = bid % 60;
    int m0 = (rem / 15) * 64, n0 = (rem % 15) * 32;
    const float* W = (zi == 0) ? Wq : (zi == 1 ? Wk : Wv);
    float* o = ws + zi * 94080;
    __shared__ float As[2][16][68];
    __shared__ float Bs[2][16][36];
    int tid = threadIdx.x;
    int ty = tid >> 4, tx = tid & 15;
    float a00=0,a01=0,a10=0,a11=0,a20=0,a21=0,a30=0,a31=0;
    const float4 z4 = make_float4(0,0,0,0);
    // A-stager: thread covers (mrow, kq..kq+3); B-stager: tid<128 covers (kk, nq..nq+3)
    int mrow = tid >> 2, kq = (tid & 3) * 4;
    bool am = (m0 + mrow) < N_TOK;
    const float* aptr = embC + (m0 + mrow) * 480 + kq;
    bool bact = tid < 128;
    int kk = tid >> 3, nq = (tid & 7) * 4;
    const float* bptr = W + kk * 480 + n0 + nq;
    const int NS = 30;
    // step 0 -> buf0
    float4 ra = am ? *(const float4*)(aptr) : z4;
    float4 rb = bact ? *(const float4*)(bptr) : z4;
    As[0][kq+0][mrow]=ra.x; As[0][kq+1][mrow]=ra.y; As[0][kq+2][mrow]=ra.z; As[0][kq+3][mrow]=ra.w;
    if (bact) *(float4*)&Bs[0][kk][nq] = rb;
    // prefetch step 1
    ra = am ? *(const float4*)(aptr + 16) : z4;
    rb = bact ? *(const float4*)(bptr + 16*480) : z4;
    __syncthreads();
    for (int s = 0; s < NS; ++s) {
        int b = s & 1;
        float4 fa = z4, fb = z4;
        if (s + 2 < NS) {
            fa = am ? *(const float4*)(aptr + (s+2)*16) : z4;
            fb = bact ? *(const float4*)(bptr + (s+2)*16*480) : z4;
        }
        GEMM_COMPUTE(As[b], Bs[b]);
        if (s + 1 < NS) {
            int nb = b ^ 1;
            As[nb][kq+0][mrow]=ra.x; As[nb][kq+1][mrow]=ra.y; As[nb][kq+2][mrow]=ra.z; As[nb][kq+3][mrow]=ra.w;
            if (bact) *(float4*)&Bs[nb][kk][nq] = rb;
        }
        __syncthreads();
        ra = fa; rb = fb;
    }
    int m = m0 + ty*4, n = n0 + tx*2;
    if (m   < N_TOK) *(float2*)(o + (m  )*480 + n) = make_float2(a00, a01);
    if (m+1 < N_TOK) *(float2*)(o + (m+1)*480 + n) = make_float2(a10, a11);
    if (m+2 < N_TOK) *(float2*)(o + (m+2)*480 + n) = make_float2(a20, a21);
    if (m+3 < N_TOK) *(float2*)(o + (m+3)*480 + n) = make_float2(a30, a31);
}

// ---------------- K2: attn = Qc^T @ Kc + psi1 partials (120 blocks) ---------
// m (rows of attn) to 511: phantom rows zero-filled (feed stats!) + store-guarded.
__global__ __launch_bounds__(256) void k_attn(const float* __restrict__ Qc,
                                              const float* __restrict__ Kc,
                                              float* __restrict__ attn,
                                              float* __restrict__ Spart) {
    __shared__ float As[2][16][68];
    __shared__ float Bs[2][16][36];
    __shared__ float red[4][2];
    int tid = threadIdx.x;
    int n0 = blockIdx.x * 32, m0 = blockIdx.y * 64;
    int ty = tid >> 4, tx = tid & 15;
    float a00=0,a01=0,a10=0,a11=0,a20=0,a21=0,a30=0,a31=0;
    const float4 z4 = make_float4(0,0,0,0);
    // A-stager: (kka, mq..mq+3) from Qc[(k0+kka)*480 + m0+mq]; B: (kk, nq..)
    int kka = tid >> 4, mq = (tid & 15) * 4;
    bool amq = (m0 + mq) < 480;
    const float* aptr = Qc + kka * 480 + m0 + mq;
    bool bact = tid < 128;
    int kk = tid >> 3, nq = (tid & 7) * 4;
    const float* bptr = Kc + kk * 480 + n0 + nq;
    const int NS = 13;   // 13*16 = 208 >= 196
    float4 ra = (amq && kka < N_TOK) ? *(const float4*)(aptr) : z4;
    float4 rb = (bact && kk < N_TOK) ? *(const float4*)(bptr) : z4;
    *(float4*)&As[0][kka][mq] = ra;
    if (bact) *(float4*)&Bs[0][kk][nq] = rb;
    ra = (amq && 16 + kka < N_TOK) ? *(const float4*)(aptr + 16*480) : z4;
    rb = (bact && 16 + kk < N_TOK) ? *(const float4*)(bptr + 16*480) : z4;
    __syncthreads();
    for (int s = 0; s < NS; ++s) {
        int b = s & 1;
        float4 fa = z4, fb = z4;
        if (s + 2 < NS) {
            int k0 = (s + 2) * 16;
            fa = (amq && k0 + kka < N_TOK) ? *(const float4*)(aptr + k0*480) : z4;
            fb = (bact && k0 + kk < N_TOK) ? *(const float4*)(bptr + k0*480) : z4;
        }
        GEMM_COMPUTE(As[b], Bs[b]);
        if (s + 1 < NS) {
            int nb = b ^ 1;
            *(float4*)&As[nb][kka][mq] = ra;
            if (bact) *(float4*)&Bs[nb][kk][nq] = rb;
        }
        __syncthreads();
        ra = fa; rb = fb;
    }
    int m = m0 + ty*4, n = n0 + tx*2;
    if (m   < 480) *(float2*)(attn + (m  )*480 + n) = make_float2(a00, a01);
    if (m+1 < 480) *(float2*)(attn + (m+1)*480 + n) = make_float2(a10, a11);
    if (m+2 < 480) *(float2*)(attn + (m+2)*480 + n) = make_float2(a20, a21);
    if (m+3 < 480) *(float2*)(attn + (m+3)*480 + n) = make_float2(a30, a31);
    // psi1 stats (phantom rows contribute exact zeros)
    float ls = a00+a01+a10+a11+a20+a21+a30+a31;
    float lq = a00*a00+a01*a01+a10*a10+a11*a11+a20*a20+a21*a21+a30*a30+a31*a31;
    #pragma unroll
    for (int o = 32; o > 0; o >>= 1) { ls += __shfl_xor(ls, o, 64); lq += __shfl_xor(lq, o, 64); }
    int wid = tid >> 6, lane = tid & 63;
    if (lane == 0) { red[wid][0] = ls; red[wid][1] = lq; }
    __syncthreads();
    if (tid == 0) {
        int bid = blockIdx.y * gridDim.x + blockIdx.x;
        Spart[bid*2]   = red[0][0] + red[1][0] + red[2][0] + red[3][0];
        Spart[bid*2+1] = red[0][1] + red[1][1] + red[2][1] + red[3][1];
    }
}

// ------- K3: fused softmax + T_hat GEMM + KV projection + kpart (60 blocks) -
// sim never materialized: B-tile = exp2(s2*attn - M2[c]) * INV[c] at staging.
__global__ __launch_bounds__(256) void k_thatkv(const float* __restrict__ Vc,
                                                const float* __restrict__ attn,
                                                const float* __restrict__ Spart,
                                                const float* __restrict__ g1,
                                                const float* __restrict__ Wk,
                                                const float* __restrict__ Wv,
                                                float2* __restrict__ KV,
                                                float* __restrict__ kpart) {
    __shared__ float As[2][16][68];
    __shared__ float Bs[2][16][36];
    __shared__ float red[4][16];
    __shared__ float M2s[32], INVs[32];
    __shared__ float Tile[64][33];
    int bid = blockIdx.x;
    int n0 = (bid % 15) * 32, m0 = (bid / 15) * 64;
    int tid = threadIdx.x;
    int wid = tid >> 6, lane = tid & 63;
    // ---- psi1 scale from partials ----
    float ps = 0.f, pq = 0.f;
    if (tid < 120) { ps = Spart[tid*2]; pq = Spart[tid*2+1]; }
    #pragma unroll
    for (int o = 32; o > 0; o >>= 1) { ps += __shfl_xor(ps, o, 64); pq += __shfl_xor(pq, o, 64); }
    if (lane == 0) { red[wid][0] = ps; red[wid][1] = pq; }
    __syncthreads();
    float S  = red[0][0] + red[1][0] + red[2][0] + red[3][0];
    float SQ = red[0][1] + red[1][1] + red[2][1] + red[3][1];
    const float invCC = 1.f / (480.f * 480.f);
    float mean = S * invCC;
    float var  = SQ * invCC - mean * mean;
    float s2 = g1[0] * rsqrtf(var + EPSN) * LOG2E;   // exp2-domain scale
    // ---- row stats for this block's 32 rows (c = n0..n0+31) ----
    // 8 rows in flight: 32-lane group per row, coalesced
    int g = tid >> 5, l32 = tid & 31;
    #pragma unroll 1
    for (int batch = 0; batch < 4; ++batch) {
        int r = batch * 8 + g;
        const float* rowp = attn + (n0 + r) * 480 + l32;
        float mx = -INFINITY;
        #pragma unroll
        for (int p = 0; p < 15; ++p) mx = fmaxf(mx, s2 * rowp[p*32]);
        #pragma unroll
        for (int o = 16; o > 0; o >>= 1) mx = fmaxf(mx, __shfl_xor(mx, o, 64));
        if (l32 == 0) M2s[r] = mx;
    }
    __syncthreads();
    #pragma unroll 1
    for (int batch = 0; batch < 4; ++batch) {
        int r = batch * 8 + g;
        const float* rowp = attn + (n0 + r) * 480 + l32;
        float m2 = M2s[r];
        float sm = 0.f;
        #pragma unroll
        for (int p = 0; p < 15; ++p) sm += fast_exp2(fmaf(s2, rowp[p*32], -m2));
        #pragma unroll
        for (int o = 16; o > 0; o >>= 1) sm += __shfl_xor(sm, o, 64);
        if (l32 == 0) INVs[r] = 1.f / sm;
    }
    __syncthreads();
    // ---- double-buffered GEMM: A=Vc (tokens x d), B=sim-on-the-fly ----
    int ty = tid >> 4, tx = tid & 15;
    float a00=0,a01=0,a10=0,a11=0,a20=0,a21=0,a30=0,a31=0;
    const float4 z4 = make_float4(0,0,0,0);
    int mrow = tid >> 2, kq = (tid & 3) * 4;
    bool am = (m0 + mrow) < N_TOK;
    const float* aptr = Vc + (m0 + mrow) * 480 + kq;
    bool bact = tid < 128;
    int nrow = tid >> 2, bkq = (tid & 3) * 4;   // only meaningful for tid<128
    const float* bptr = attn + (n0 + nrow) * 480 + bkq;
    float nM2r = 0.f, invr = 0.f;
    if (bact) { nM2r = -M2s[nrow]; invr = INVs[nrow]; }
    const int NS = 30;
    float4 ra = am ? *(const float4*)(aptr) : z4;
    float4 rb = bact ? *(const float4*)(bptr) : z4;
    As[0][kq+0][mrow]=ra.x; As[0][kq+1][mrow]=ra.y; As[0][kq+2][mrow]=ra.z; As[0][kq+3][mrow]=ra.w;
    if (bact) {
        Bs[0][bkq+0][nrow] = fast_exp2(fmaf(s2, rb.x, nM2r)) * invr;
        Bs[0][bkq+1][nrow] = fast_exp2(fmaf(s2, rb.y, nM2r)) * invr;
        Bs[0][bkq+2][nrow] = fast_exp2(fmaf(s2, rb.z, nM2r)) * invr;
        Bs[0][bkq+3][nrow] = fast_exp2(fmaf(s2, rb.w, nM2r)) * invr;
    }
    ra = am ? *(const float4*)(aptr + 16) : z4;
    rb = bact ? *(const float4*)(bptr + 16) : z4;
    __syncthreads();
    for (int s = 0; s < NS; ++s) {
        int b = s & 1;
        float4 fa = z4, fb = z4;
        if (s + 2 < NS) {
            fa = am ? *(const float4*)(aptr + (s+2)*16) : z4;
            fb = bact ? *(const float4*)(bptr + (s+2)*16) : z4;
        }
        GEMM_COMPUTE(As[b], Bs[b]);
        if (s + 1 < NS) {
            int nb = b ^ 1;
            As[nb][kq+0][mrow]=ra.x; As[nb][kq+1][mrow]=ra.y; As[nb][kq+2][mrow]=ra.z; As[nb][kq+3][mrow]=ra.w;
            if (bact) {
                Bs[nb][bkq+0][nrow] = fast_exp2(fmaf(s2, rb.x, nM2r)) * invr;
                Bs[nb][bkq+1][nrow] = fast_exp2(fmaf(s2, rb.y, nM2r)) * invr;
                Bs[nb][bkq+2][nrow] = fast_exp2(fmaf(s2, rb.z, nM2r)) * invr;
                Bs[nb][bkq+3][nrow] = fast_exp2(fmaf(s2, rb.w, nM2r)) * invr;
            }
        }
        __syncthreads();
        ra = fa; rb = fb;
    }
    // ---- stage tile, project to K/V, per-block k-stats (round-6 P3 code) ---
    int r0 = ty*4, cc = tx*2;
    Tile[r0+0][cc] = a00; Tile[r0+0][cc+1] = a01;
    Tile[r0+1][cc] = a10; Tile[r0+1][cc+1] = a11;
    Tile[r0+2][cc] = a20; Tile[r0+2][cc+1] = a21;
    Tile[r0+3][cc] = a30; Tile[r0+3][cc+1] = a31;
    __syncthreads();
    float su[4] = {0,0,0,0}, sq[4] = {0,0,0,0};
    float mx[4] = {-INFINITY,-INFINITY,-INFINITY,-INFINITY};
    float mn[4] = { INFINITY, INFINITY, INFINITY, INFINITY};
    #pragma unroll
    for (int rep = 0; rep < 2; ++rep) {
        int e = tid + rep * 256;
        int t = e >> 3, jj = e & 7;
        int tok = m0 + t;
        bool act = tok < N_TOK;
        float c0 = Tile[t][4*jj], c1 = Tile[t][4*jj+1];
        float c2 = Tile[t][4*jj+2], c3 = Tile[t][4*jj+3];
        int m_kv = (n0/4 + jj) * 196 + tok;
        #pragma unroll
        for (int h = 0; h < 4; ++h) {
            float kh = c0*Wk[h] + c1*Wk[4+h] + c2*Wk[8+h] + c3*Wk[12+h];
            float vh = c0*Wv[h] + c1*Wv[4+h] + c2*Wv[8+h] + c3*Wv[12+h];
            if (act) {
                KV[h * M_KV + m_kv] = make_float2(kh, vh);
                su[h] += kh; sq[h] += kh * kh;
                mx[h] = fmaxf(mx[h], kh); mn[h] = fminf(mn[h], kh);
            }
        }
    }
    #pragma unroll
    for (int h = 0; h < 4; ++h) {
        #pragma unroll
        for (int o = 32; o > 0; o >>= 1) {
            su[h] += __shfl_xor(su[h], o, 64);
            sq[h] += __shfl_xor(sq[h], o, 64);
            mx[h] = fmaxf(mx[h], __shfl_xor(mx[h], o, 64));
            mn[h] = fminf(mn[h], __shfl_xor(mn[h], o, 64));
        }
        if (lane == 0) {
            red[wid][h*4+0] = su[h]; red[wid][h*4+1] = sq[h];
            red[wid][h*4+2] = mx[h]; red[wid][h*4+3] = mn[h];
        }
    }
    __syncthreads();
    if (tid < 16) {
        int h = tid & 3, st = tid >> 2;
        float v0 = red[0][h*4+st], v1 = red[1][h*4+st], v2 = red[2][h*4+st], v3 = red[3][h*4+st];
        float r;
        if (st < 2)       r = v0 + v1 + v2 + v3;
        else if (st == 2) r = fmaxf(fmaxf(v0, v1), fmaxf(v2, v3));
        else              r = fminf(fminf(v0, v1), fminf(v2, v3));
        kpart[st * 256 + h * 64 + bid] = r;
    }
}

// -------- K4: branch attention, inline row stats, split-k slabs (896 blocks)
__global__ __launch_bounds__(256) void k_branch(
        const float* __restrict__ emb1, const float* __restrict__ emb2,
        const float* __restrict__ emb3, const float* __restrict__ emb4,
        const float* __restrict__ Wq1, const float* __restrict__ Wq2,
        const float* __restrict__ Wq3, const float* __restrict__ Wq4,
        const float* __restrict__ g2v,
        const float2* __restrict__ KV, const float* __restrict__ kpart,
        float* __restrict__ Lslab, float* __restrict__ Cslab) {
    __shared__ float red[4][16];
    int tid = threadIdx.x;
    int wid = tid >> 6, lane = tid & 63;
    int rq = blockIdx.y;
    int row = rq / 7, qg = rq % 7;
    int chunk = blockIdx.x;
    int i = row >> 2, h = row & 3;
    const float* emb = (i == 0) ? emb1 : (i == 1) ? emb2 : (i == 2) ? emb3 : emb4;
    const float* Wq  = (i == 0) ? Wq1 : (i == 1) ? Wq2 : (i == 2) ? Wq3 : Wq4;
    bool actq = tid < 196;
    float Q = 0.f;
    if (actq) {
        Q = emb[tid*4]*Wq[h] + emb[tid*4+1]*Wq[4+h] +
            emb[tid*4+2]*Wq[8+h] + emb[tid*4+3]*Wq[12+h];
    }
    float s = actq ? Q : 0.f, s2 = actq ? Q*Q : 0.f;
    float ks = 0.f, kq2 = 0.f, km = -INFINITY, kn = INFINITY;
    if (tid < 60) {
        ks  = kpart[0*256 + h*64 + tid];
        kq2 = kpart[1*256 + h*64 + tid];
        km  = kpart[2*256 + h*64 + tid];
        kn  = kpart[3*256 + h*64 + tid];
    }
    #pragma unroll
    for (int o = 32; o > 0; o >>= 1) {
        s += __shfl_xor(s, o, 64); s2 += __shfl_xor(s2, o, 64);
        ks += __shfl_xor(ks, o, 64); kq2 += __shfl_xor(kq2, o, 64);
        km = fmaxf(km, __shfl_xor(km, o, 64)); kn = fminf(kn, __shfl_xor(kn, o, 64));
    }
    if (lane == 0) {
        red[wid][0] = s;  red[wid][1] = s2; red[wid][2] = ks;
        red[wid][3] = kq2; red[wid][4] = km; red[wid][5] = kn;
    }
    __syncthreads();
    float sumQ  = red[0][0] + red[1][0] + red[2][0] + red[3][0];
    float sumQ2 = red[0][1] + red[1][1] + red[2][1] + red[3][1];
    float Ksum  = red[0][2] + red[1][2] + red[2][2] + red[3][2];
    float Ksq   = red[0][3] + red[1][3] + red[2][3] + red[3][3];
    float Kmax  = fmaxf(fmaxf(red[0][4], red[1][4]), fmaxf(red[2][4], red[3][4]));
    float Kmin  = fminf(fminf(red[0][5], red[1][5]), fminf(red[2][5], red[3][5]));
    float Qbar = sumQ * (1.f/196.f), Q2bar = sumQ2 * (1.f/196.f);
    float Kbar = Ksum * (1.f/(float)M_KV), K2bar = Ksq * (1.f/(float)M_KV);
    float mu = Qbar * Kbar;
    float var = Q2bar * K2bar - mu * mu;
    float sc = g2v[h] * rsqrtf(var + EPSN);
    int qbase = qg * 28 + wid * 7;
    float B2[7], nM2[7];
    #pragma unroll
    for (int j = 0; j < 7; ++j) {
        int q = qbase + j;
        float Qj = emb[q*4]*Wq[h] + emb[q*4+1]*Wq[4+h] +
                   emb[q*4+2]*Wq[8+h] + emb[q*4+3]*Wq[12+h];
        float b = Qj * sc;
        float M = (b >= 0.f) ? b * Kmax : b * Kmin;
        B2[j]  = b * LOG2E;
        nM2[j] = -M * LOG2E;
    }
    const float2* kvp = KV + h * M_KV;
    int kbase = chunk * CH, kend = kbase + CH;
    float l[7] = {0,0,0,0,0,0,0};
    float a[7] = {0,0,0,0,0,0,0};
#define PROC(P) { \
        _Pragma("unroll") \
        for (int j = 0; j < 7; ++j) { \
            float x = fast_exp2(fmaf(B2[j], P.x, nM2[j])); \
            l[j] += x; \
            a[j] = fmaf(x, P.y, a[j]); \
        } }
    int k = kbase + lane;
    for (; k + 192 < kend; k += 256) {   // 4 loads in flight
        float2 p0 = kvp[k], p1 = kvp[k+64], p2 = kvp[k+128], p3 = kvp[k+192];
        PROC(p0); PROC(p1); PROC(p2); PROC(p3);
    }
    for (; k < kend; k += 64) { float2 p = kvp[k]; PROC(p); }
#undef PROC
    int sbase = (chunk * 16 + row) * 196 + qbase;
    #pragma unroll
    for (int j = 0; j < 7; ++j) {
        float lv = l[j], av = a[j];
        #pragma unroll
        for (int o = 32; o > 0; o >>= 1) { lv += __shfl_xor(lv, o, 64); av += __shfl_xor(av, o, 64); }
        if (lane == 0) {
            Lslab[sbase + j] = lv;
            Cslab[sbase + j] = av;
        }
    }
}

// ---------------- K5: finalize: sum slabs, c = C/L, out = c @ Wo ------------
__global__ __launch_bounds__(256) void k_final(const float* __restrict__ Lslab,
                                               const float* __restrict__ Cslab,
                                               const float* __restrict__ o0, const float* __restrict__ o1,
                                               const float* __restrict__ o2, const float* __restrict__ o3,
                                               float* __restrict__ out) {
    int i = blockIdx.x;
    int q = threadIdx.x;
    if (q >= 196) return;
    const float* Wo = (i == 0) ? o0 : (i == 1) ? o1 : (i == 2) ? o2 : o3;
    float c[4];
    #pragma unroll
    for (int h = 0; h < 4; ++h) {
        float L = 0.f, Cc = 0.f;
        #pragma unroll
        for (int ch = 0; ch < CHUNKS; ++ch) {
            int idx = (ch * 16 + i * 4 + h) * 196 + q;
            L  += Lslab[idx];
            Cc += Cslab[idx];
        }
        c[h] = Cc / L;
    }
    float4 o;
    o.x = c[0]*Wo[0] + c[1]*Wo[4] + c[2]*Wo[8]  + c[3]*Wo[12];
    o.y = c[0]*Wo[1] + c[1]*Wo[5] + c[2]*Wo[9]  + c[3]*Wo[13];
    o.z = c[0]*Wo[2] + c[1]*Wo[6] + c[2]*Wo[10] + c[3]*Wo[14];
    o.w = c[0]*Wo[3] + c[1]*Wo[7] + c[2]*Wo[11] + c[3]*Wo[15];
    *(float4*)(out + i * 784 + q * 4) = o;
}

extern "C" void kernel_launch(void* const* d_in, const int* in_sizes, int n_in,
                              void* d_out, int out_size, void* d_ws, size_t ws_size,
                              hipStream_t stream) {
    const float* emb1 = (const float*)d_in[0];
    const float* emb2 = (const float*)d_in[1];
    const float* emb3 = (const float*)d_in[2];
    const float* emb4 = (const float*)d_in[3];
    const float* embC = (const float*)d_in[4];
    const float* WqC  = (const float*)d_in[5];
    const float* WkC  = (const float*)d_in[6];
    const float* WvC  = (const float*)d_in[7];
    const float* Wq1  = (const float*)d_in[8];
    const float* Wq2  = (const float*)d_in[9];
    const float* Wq3  = (const float*)d_in[10];
    const float* Wq4  = (const float*)d_in[11];
    const float* Wk   = (const float*)d_in[12];
    const float* Wv   = (const float*)d_in[13];
    const float* Wo1  = (const float*)d_in[14];
    const float* Wo2  = (const float*)d_in[15];
    const float* Wo3  = (const float*)d_in[16];
    const float* Wo4  = (const float*)d_in[17];
    const float* g1   = (const float*)d_in[18];
    const float* g2   = (const float*)d_in[20];
    float* ws = (float*)d_ws;
    float* out = (float*)d_out;

    k_qkv<<<180, 256, 0, stream>>>(embC, WqC, WkC, WvC, ws);
    k_attn<<<dim3(15, 8), 256, 0, stream>>>(ws + OFF_QC, ws + OFF_KC,
                                            ws + OFF_ATTN, ws + OFF_SPART);
    k_thatkv<<<60, 256, 0, stream>>>(ws + OFF_VC, ws + OFF_ATTN, ws + OFF_SPART, g1,
                                     Wk, Wv, (float2*)(ws + OFF_KV), ws + OFF_KPART);
    k_branch<<<dim3(CHUNKS, 112), 256, 0, stream>>>(emb1, emb2, emb3, emb4,
                                                    Wq1, Wq2, Wq3, Wq4, g2,
                                                    (const float2*)(ws + OFF_KV), ws + OFF_KPART,
                                                    ws + OFF_LSLAB, ws + OFF_CSLAB);
    k_final<<<4, 256, 0, stream>>>(ws + OFF_LSLAB, ws + OFF_CSLAB, Wo1, Wo2, Wo3, Wo4, out);
}